// Round 4
// baseline (276.896 us; speedup 1.0000x reference)
//
#include <hip/hip_runtime.h>
#include <math.h>

#define DIM   128
#define SLICE (DIM*DIM)       // 16384
#define VOL   (DIM*DIM*DIM)   // 2097152
#define NB    2
#define NK    4
#define NVOL  (NB*NK)         // 8

// Gaussian taps exp(-x^2/(2*5^2)), x=-4..4 (unnormalized, matches reference)
__constant__ float c_g[9] = {
    0.72614904f, 0.83527021f, 0.92311635f, 0.98019867f, 1.0f,
    0.98019867f, 0.92311635f, 0.83527021f, 0.72614904f
};

#define RSTR 33   // LDS row stride in float4 (+1 pad breaks row bank aliasing)

// K1: one block per (vol, d, 32-row h-chunk). Single barrier.
// w-blur from 3 overlapping global float4 windows (L1-served), wh tile to LDS,
// h-blur via 12-row register ring, float4 store. Slice sums fused.
__global__ __launch_bounds__(256, 4) void k_slice(
    const float* __restrict__ labels, const float* __restrict__ inputs,
    float* __restrict__ A, float* __restrict__ red)
{
    __shared__ float4 sT4[40*RSTR];   // 21120 B
    __shared__ float sRed[8];
    const int hc  = blockIdx.x & 3;
    const int d   = (blockIdx.x >> 2) & 127;
    const int vol = blockIdx.x >> 9;
    const int b   = vol >> 2;
    const int h0  = hc * 32;
    const float* __restrict__ src  = labels + (size_t)vol*VOL + (size_t)d*SLICE;
    const float* __restrict__ isrc = inputs + (size_t)b  *VOL + (size_t)d*SLICE;
    float* __restrict__ dst = A + (size_t)vol*VOL + (size_t)d*SLICE;
    const int t = threadIdx.x;
    const float g1 = c_g[5], g2 = c_g[6], g3 = c_g[7], g4 = c_g[8];
    const float4 z4 = make_float4(0.f,0.f,0.f,0.f);

    // Phase A: all global loads issued with no inter-dependencies.
    float sp = 0.f, sip = 0.f;
    float4 wb[5];
    #pragma unroll
    for (int j = 0; j < 5; ++j) {
        const int i = t + j*256;                    // 40*32 float4 sites
        const int r = i >> 5, c = i & 31;
        const int h = h0 - 4 + r;                   // global row
        float4 pv = z4, cv = z4, nx = z4;
        if (h >= 0 && h < 128) {
            const float4* row = (const float4*)(src + h*128);
            cv = row[c];
            if (c > 0)  pv = row[c-1];
            if (c < 31) nx = row[c+1];
            if (r >= 4 && r < 36) {                 // owned row: fuse sums
                const float4 iv = ((const float4*)(isrc + h*128))[c];
                sp  += cv.x + cv.y + cv.z + cv.w;
                sip += cv.x*iv.x + cv.y*iv.y + cv.z*iv.z + cv.w*iv.w;
            }
        }
        float4 o;
        o.x = cv.x + g1*(pv.w + cv.y) + g2*(pv.z + cv.z) + g3*(pv.y + cv.w) + g4*(pv.x + nx.x);
        o.y = cv.y + g1*(cv.x + cv.z) + g2*(pv.w + cv.w) + g3*(pv.z + nx.x) + g4*(pv.y + nx.y);
        o.z = cv.z + g1*(cv.y + cv.w) + g2*(cv.x + nx.x) + g3*(pv.w + nx.y) + g4*(pv.z + nx.z);
        o.w = cv.w + g1*(cv.z + nx.x) + g2*(cv.y + nx.y) + g3*(cv.x + nx.z) + g4*(pv.w + nx.w);
        wb[j] = o;
        sT4[r*RSTR + c] = o;
    }
    #pragma unroll
    for (int o = 32; o; o >>= 1) { sp += __shfl_down(sp, o); sip += __shfl_down(sip, o); }
    if ((t & 63) == 0) { sRed[t >> 6] = sp; sRed[4 + (t >> 6)] = sip; }
    __syncthreads();                                 // the ONLY barrier

    if (t == 0) {
        atomicAdd(&red[vol],   sRed[0]+sRed[1]+sRed[2]+sRed[3]);
        atomicAdd(&red[8+vol], sRed[4]+sRed[5]+sRed[6]+sRed[7]);
    }

    // Phase B: h-blur via 12-row register ring -> 4 output rows per thread
    {
        const int c = t & 31;       // float4 column
        const int g = t >> 5;       // row group 0..7
        float4 r0[12];
        #pragma unroll
        for (int j = 0; j < 12; ++j) r0[j] = sT4[(g*4 + j)*RSTR + c];
        #pragma unroll
        for (int k = 0; k < 4; ++k) {
            float4 acc = r0[4+k];
            #pragma unroll
            for (int dt = 1; dt <= 4; ++dt) {
                const float g_ = c_g[4+dt];
                acc.x += g_*(r0[4+k-dt].x + r0[4+k+dt].x);
                acc.y += g_*(r0[4+k-dt].y + r0[4+k+dt].y);
                acc.z += g_*(r0[4+k-dt].z + r0[4+k+dt].z);
                acc.w += g_*(r0[4+k-dt].w + r0[4+k+dt].w);
            }
            ((float4*)(dst + (h0 + g*4 + k)*128))[c] = acc;
        }
    }
}

// K2: d-blur of A via a float2 9-register ring, fused with weights + reductions.
// Block: 4 h-rows x 128 w (float2/lane); d in 8 chunks of 16 -> 2048 blocks.
__global__ __launch_bounds__(256, 4) void k_dblur_reduce(
    const float* __restrict__ A, const float* __restrict__ labels,
    const float* __restrict__ inputs, const float* __restrict__ red,
    float* __restrict__ nd)
{
    const int dc  = blockIdx.x & 7;
    const int hcc = (blockIdx.x >> 3) & 31;
    const int vol = blockIdx.x >> 8;
    const int b = vol >> 2, k = vol & 3;
    const int row = threadIdx.x >> 6;               // 0..3
    const int l   = threadIdx.x & 63;               // float2 column 0..63
    const int h   = hcc*4 + row;
    const size_t base = (size_t)vol*VOL + (size_t)h*128 + l*2;
    const float2* __restrict__ A2 = (const float2*)(A + base);
    const float2* __restrict__ P2 = (const float2*)(labels + base);
    const float2* __restrict__ I2 = (const float2*)(inputs + (size_t)b*VOL + (size_t)h*128 + l*2);

    // class mean = sumIP / (sumP + 1e-5*V)
    const float mean = red[8+vol] / (red[vol] + 20.97152f);
    const int d0 = dc * 16;

    float2 ring[9];
    #pragma unroll
    for (int i = 0; i < 9; ++i) ring[i] = make_float2(0.f, 0.f);
    float numAcc = 0.f, denAcc = 0.f;

    #pragma unroll 6
    for (int it = 0; it < 24; ++it) {
        const int s = d0 - 4 + it;
        float2 v = make_float2(0.f, 0.f);
        if ((unsigned)s < 128u) v = A2[(size_t)s * (SLICE/2)];
        #pragma unroll
        for (int i = 0; i < 8; ++i) ring[i] = ring[i+1];
        ring[8] = v;
        if (it >= 8) {
            const int dcur = s - 4;                 // d0 .. d0+15
            float2 B = ring[4];                     // center tap = 1.0
            #pragma unroll
            for (int dt = 1; dt <= 4; ++dt) {
                const float g = c_g[4+dt];
                B.x += g*(ring[4+dt].x + ring[4-dt].x);
                B.y += g*(ring[4+dt].y + ring[4-dt].y);
            }
            const float2 p  = P2[(size_t)dcur * (SLICE/2)];
            const float2 iv = I2[(size_t)dcur * (SLICE/2)];
            { float df = iv.x - mean; df *= df; const float bw = B.x * __expf(-df*df); numAcc += bw * p.x; denAcc += bw; }
            { float df = iv.y - mean; df *= df; const float bw = B.y * __expf(-df*df); numAcc += bw * p.y; denAcc += bw; }
        }
    }

    #pragma unroll
    for (int o = 32; o; o >>= 1) { numAcc += __shfl_down(numAcc, o); denAcc += __shfl_down(denAcc, o); }
    __shared__ float sN[4], sD[4];
    const int wid = threadIdx.x >> 6;
    if ((threadIdx.x & 63) == 0) { sN[wid] = numAcc; sD[wid] = denAcc; }
    __syncthreads();
    if (threadIdx.x == 0) {
        atomicAdd(&nd[k],   sN[0]+sN[1]+sN[2]+sN[3]);
        atomicAdd(&nd[4+k], sD[0]+sD[1]+sD[2]+sD[3]);
    }
}

__global__ void k_final(const float* __restrict__ red, float* __restrict__ out)
{
    float loss = 0.f;
    #pragma unroll
    for (int k = 0; k < 4; ++k) loss += fabsf(red[16+k] / (red[20+k] + 1e-6f));
    out[0] = (float)NK - loss;
}

extern "C" void kernel_launch(void* const* d_in, const int* in_sizes, int n_in,
                              void* d_out, int out_size, void* d_ws, size_t ws_size,
                              hipStream_t stream)
{
    const float* labels = (const float*)d_in[0];   // (2,4,128,128,128)
    const float* inputs = (const float*)d_in[1];   // (2,1,128,128,128)
    float* out = (float*)d_out;
    float* red = (float*)d_ws;
    float* A   = (float*)((char*)d_ws + 256);      // 64 MiB wh-blurred labels

    hipMemsetAsync(red, 0, 24*sizeof(float), stream);
    k_slice<<<NVOL*DIM*4, 256, 0, stream>>>(labels, inputs, A, red);
    k_dblur_reduce<<<NVOL*32*8, 256, 0, stream>>>(A, labels, inputs, red, red + 16);
    k_final<<<1, 1, 0, stream>>>(red, out);
}

// Round 5
// 184.596 us; speedup vs baseline: 1.5000x; 1.5000x over previous
//
#include <hip/hip_runtime.h>
#include <math.h>

#define DIM   128
#define SLICE (DIM*DIM)       // 16384
#define VOL   (DIM*DIM*DIM)   // 2097152
#define NK    4
#define NVOL  8
#define SSTR  33              // staging row stride in float4

// Gaussian taps exp(-x^2/(2*5^2)), x=-4..4 (unnormalized, matches reference)
__constant__ float c_g[9] = {
    0.72614904f, 0.83527021f, 0.92311635f, 0.98019867f, 1.0f,
    0.98019867f, 0.92311635f, 0.83527021f, 0.72614904f
};

// ws layout (floats): [0..7] sumP per vol, [8..15] sumIP per vol,
//                     [16..19] num per class, [20..23] den per class

// K1: pure-stream sums. 1024 blocks: b = blk>>9, 512 chunks per volume.
// Reads inputs once, labels once (4 class streams), sequential float4.
__global__ __launch_bounds__(256) void k_sums(
    const float* __restrict__ labels, const float* __restrict__ inputs,
    float* __restrict__ red)
{
    const int b     = blockIdx.x >> 9;
    const int chunk = blockIdx.x & 511;
    const int t     = threadIdx.x;
    const size_t off4 = (size_t)chunk*1024 + t;
    const float4* __restrict__ I4 = (const float4*)inputs + (size_t)b*(VOL/4) + off4;
    const float4* __restrict__ L4 = (const float4*)labels;
    float sp[4] = {0,0,0,0}, sip[4] = {0,0,0,0};
    #pragma unroll
    for (int j = 0; j < 4; ++j) {
        const float4 iv = I4[j*256];
        #pragma unroll
        for (int k = 0; k < 4; ++k) {
            const float4 p = L4[(size_t)(b*NK + k)*(VOL/4) + off4 + j*256];
            sp[k]  += p.x + p.y + p.z + p.w;
            sip[k] += p.x*iv.x + p.y*iv.y + p.z*iv.z + p.w*iv.w;
        }
    }
    #pragma unroll
    for (int k = 0; k < 4; ++k) {
        #pragma unroll
        for (int o = 32; o; o >>= 1) {
            sp[k]  += __shfl_down(sp[k],  o);
            sip[k] += __shfl_down(sip[k], o);
        }
    }
    __shared__ float sB[8][4];
    const int wid = t >> 6;
    if ((t & 63) == 0) {
        #pragma unroll
        for (int k = 0; k < 4; ++k) { sB[k][wid] = sp[k]; sB[4+k][wid] = sip[k]; }
    }
    __syncthreads();
    if (t < 8) {
        const float v = sB[t][0] + sB[t][1] + sB[t][2] + sB[t][3];
        atomicAdd(&red[(t < 4 ? 0 : 8) + b*NK + (t & 3)], v);
    }
}

// K2: fused wh-blur + d-blur + weights + reduction. No intermediate buffer.
// Grid 512: (vol 8) x (h-strip 16 of 8 rows) x (d-quarter 4 of 32 slices).
// Streams d: per step, w-blur 16 label rows (3 overlapping global float4
// windows, L3-hot) into double-buffered LDS staging; h-blur from staging into
// a per-thread float4 ring over d; d-blur + weights + accumulate.
__global__ __launch_bounds__(256) void k_fused(
    const float* __restrict__ labels, const float* __restrict__ inputs,
    const float* __restrict__ red, float* __restrict__ nd)
{
    __shared__ float4 sW[2][16*SSTR + 8];
    __shared__ float sN[4], sD[4];

    const int dq    = blockIdx.x & 3;
    const int strip = (blockIdx.x >> 2) & 15;
    const int vol   = blockIdx.x >> 6;
    const int b = vol >> 2, kcls = vol & 3;
    const int d0 = dq * 32;
    const int t  = threadIdx.x;
    const float g1 = c_g[5], g2 = c_g[6], g3 = c_g[7], g4 = c_g[8];
    const float4 z4 = make_float4(0.f, 0.f, 0.f, 0.f);

    const float* __restrict__ src = labels + (size_t)vol*VOL;
    const float mean = red[8+vol] / (red[vol] + 20.97152f);

    // two w-blur sites per thread: (r0,c0) and (r0+8,c0), staged rows 0..15
    const int r0 = t >> 5, c0 = t & 31;
    const int r1 = r0 + 8;
    // h-blur / output site: global row strip*8+ho, float4 col wq
    const int ho = t >> 5, wq = t & 31;

    const int hA = strip*8 - 4 + r0;
    const int hB = strip*8 - 4 + r1;
    const bool vA = (unsigned)hA < 128u;
    const bool vB = (unsigned)hB < 128u;
    const float4* __restrict__ rowA = (const float4*)(src + (size_t)(vA ? hA : 0)*DIM);
    const float4* __restrict__ rowB = (const float4*)(src + (size_t)(vB ? hB : 0)*DIM);

    const size_t ob4 = (size_t)(strip*8 + ho)*(DIM/4) + wq;
    const float4* __restrict__ P4 = (const float4*)src + ob4;
    const float4* __restrict__ I4 = (const float4*)(inputs + (size_t)b*VOL) + ob4;

    float4 ring[9];
    #pragma unroll
    for (int i = 0; i < 9; ++i) ring[i] = z4;
    float numAcc = 0.f, denAcc = 0.f;

    auto ldA = [&](int s, float4& pv, float4& cv, float4& nx) {
        pv = cv = nx = z4;
        if (vA && (unsigned)s < 128u) {
            const float4* rp = rowA + (size_t)s*(SLICE/4);
            cv = rp[c0];
            if (c0 > 0)  pv = rp[c0-1];
            if (c0 < 31) nx = rp[c0+1];
        }
    };
    auto ldB = [&](int s, float4& pv, float4& cv, float4& nx) {
        pv = cv = nx = z4;
        if (vB && (unsigned)s < 128u) {
            const float4* rp = rowB + (size_t)s*(SLICE/4);
            cv = rp[c0];
            if (c0 > 0)  pv = rp[c0-1];
            if (c0 < 31) nx = rp[c0+1];
        }
    };

    float4 Apv, Acv, Anx, Bpv, Bcv, Bnx;
    ldA(d0-4, Apv, Acv, Anx);
    ldB(d0-4, Bpv, Bcv, Bnx);

    #pragma unroll 2
    for (int s = d0-4; s < d0+36; ++s) {
        const float4 apv=Apv, acv=Acv, anx=Anx, bpv=Bpv, bcv=Bcv, bnx=Bnx;
        ldA(s+1, Apv, Acv, Anx);                 // prefetch next slice windows
        ldB(s+1, Bpv, Bcv, Bnx);
        float4 pc = z4, ic = z4;
        const bool outStep = (s >= d0+4);
        if (outStep) {                           // prefetch output-voxel P, I
            pc = P4[(size_t)(s-4)*(SLICE/4)];
            ic = I4[(size_t)(s-4)*(SLICE/4)];
        }
        const int buf = s & 1;
        {   // w-blur site A
            float4 o;
            o.x = acv.x + g1*(apv.w+acv.y) + g2*(apv.z+acv.z) + g3*(apv.y+acv.w) + g4*(apv.x+anx.x);
            o.y = acv.y + g1*(acv.x+acv.z) + g2*(apv.w+acv.w) + g3*(apv.z+anx.x) + g4*(apv.y+anx.y);
            o.z = acv.z + g1*(acv.y+acv.w) + g2*(acv.x+anx.x) + g3*(apv.w+anx.y) + g4*(apv.z+anx.z);
            o.w = acv.w + g1*(acv.z+anx.x) + g2*(acv.y+anx.y) + g3*(acv.x+anx.z) + g4*(apv.w+anx.w);
            sW[buf][r0*SSTR + c0] = o;
        }
        {   // w-blur site B
            float4 o;
            o.x = bcv.x + g1*(bpv.w+bcv.y) + g2*(bpv.z+bcv.z) + g3*(bpv.y+bcv.w) + g4*(bpv.x+bnx.x);
            o.y = bcv.y + g1*(bcv.x+bcv.z) + g2*(bpv.w+bcv.w) + g3*(bpv.z+bnx.x) + g4*(bpv.y+bnx.y);
            o.z = bcv.z + g1*(bcv.y+bcv.w) + g2*(bcv.x+bnx.x) + g3*(bpv.w+bnx.y) + g4*(bpv.z+bnx.z);
            o.w = bcv.w + g1*(bcv.z+bnx.x) + g2*(bcv.y+bnx.y) + g3*(bcv.x+bnx.z) + g4*(bpv.w+bnx.w);
            sW[buf][r1*SSTR + c0] = o;
        }
        __syncthreads();                         // one barrier per step
        // h-blur at (ho,wq): staged rows (ho+4) +/- dt
        float4 acc = sW[buf][(ho+4)*SSTR + wq];
        #pragma unroll
        for (int dt = 1; dt <= 4; ++dt) {
            const float g = c_g[4+dt];
            const float4 u = sW[buf][(ho+4-dt)*SSTR + wq];
            const float4 v = sW[buf][(ho+4+dt)*SSTR + wq];
            acc.x += g*(u.x+v.x); acc.y += g*(u.y+v.y);
            acc.z += g*(u.z+v.z); acc.w += g*(u.w+v.w);
        }
        #pragma unroll
        for (int i = 0; i < 8; ++i) ring[i] = ring[i+1];
        ring[8] = acc;
        if (outStep) {
            float4 B = ring[4];
            #pragma unroll
            for (int dt = 1; dt <= 4; ++dt) {
                const float g = c_g[4+dt];
                B.x += g*(ring[4+dt].x + ring[4-dt].x);
                B.y += g*(ring[4+dt].y + ring[4-dt].y);
                B.z += g*(ring[4+dt].z + ring[4-dt].z);
                B.w += g*(ring[4+dt].w + ring[4-dt].w);
            }
            { float df = ic.x - mean; df *= df; const float bw = B.x * __expf(-df*df); numAcc += bw*pc.x; denAcc += bw; }
            { float df = ic.y - mean; df *= df; const float bw = B.y * __expf(-df*df); numAcc += bw*pc.y; denAcc += bw; }
            { float df = ic.z - mean; df *= df; const float bw = B.z * __expf(-df*df); numAcc += bw*pc.z; denAcc += bw; }
            { float df = ic.w - mean; df *= df; const float bw = B.w * __expf(-df*df); numAcc += bw*pc.w; denAcc += bw; }
        }
    }

    #pragma unroll
    for (int o = 32; o; o >>= 1) { numAcc += __shfl_down(numAcc, o); denAcc += __shfl_down(denAcc, o); }
    if ((t & 63) == 0) { sN[t >> 6] = numAcc; sD[t >> 6] = denAcc; }
    __syncthreads();
    if (t == 0) {
        atomicAdd(&nd[kcls],   sN[0]+sN[1]+sN[2]+sN[3]);
        atomicAdd(&nd[4+kcls], sD[0]+sD[1]+sD[2]+sD[3]);
    }
}

__global__ void k_final(const float* __restrict__ red, float* __restrict__ out)
{
    float loss = 0.f;
    #pragma unroll
    for (int k = 0; k < 4; ++k) loss += fabsf(red[16+k] / (red[20+k] + 1e-6f));
    out[0] = (float)NK - loss;
}

extern "C" void kernel_launch(void* const* d_in, const int* in_sizes, int n_in,
                              void* d_out, int out_size, void* d_ws, size_t ws_size,
                              hipStream_t stream)
{
    const float* labels = (const float*)d_in[0];   // (2,4,128,128,128)
    const float* inputs = (const float*)d_in[1];   // (2,1,128,128,128)
    float* out = (float*)d_out;
    float* red = (float*)d_ws;                     // 24 floats

    hipMemsetAsync(red, 0, 24*sizeof(float), stream);
    k_sums<<<2*512, 256, 0, stream>>>(labels, inputs, red);
    k_fused<<<NVOL*16*4, 256, 0, stream>>>(labels, inputs, red, red + 16);
    k_final<<<1, 1, 0, stream>>>(red, out);
}